// Round 12
// baseline (215.591 us; speedup 1.0000x reference)
//
#include <hip/hip_runtime.h>
#include <hip/hip_bf16.h>
#include <stdint.h>

// ---------------- types / helpers ----------------
typedef __attribute__((ext_vector_type(8))) short bf16x8;
typedef __attribute__((ext_vector_type(4))) float f32x4;
typedef __attribute__((ext_vector_type(4))) int   i32x4;

#define DEV static __device__ __forceinline__

DEV float bf2f(short s) {
    unsigned u = ((unsigned)(unsigned short)s) << 16;
    return __builtin_bit_cast(float, u);
}
DEV short f2bf(float f) {  // RNE (software; prep paths)
    unsigned u = __builtin_bit_cast(unsigned, f);
    unsigned r = u + 0x7fffu + ((u >> 16) & 1u);
    return (short)(r >> 16);
}
DEV unsigned cvt_pk_bf16(float lo, float hi) {  // single HW instr
    unsigned r;
    asm("v_cvt_pk_bf16_f32 %0, %1, %2" : "=v"(r) : "v"(lo), "v"(hi));
    return r;
}

// problem constants
#define PTOT 32768
#define NEXP2 (-2.885390081777927f)   // -2*log2(e)

// ws byte offsets
#define WS_WC1F 0          // wc1f: 16384 shorts
#define WS_WC2F 32768      // wc2f: 16384 shorts
#define WS_WD1F 65536      // wd1f: 147456 shorts
#define WS_WF   360448     // Wf:   589824 shorts
#define WS_EKT  1540096
#define WS_EN   2719744
#define WS_XT   19496960   // xT8: 8*66*32*66*8 bf16 = 17842176 B ; total ~37.3 MB

// ---------------- prep: fragment-major weight reorder + bf16 cast ----------------
__global__ __launch_bounds__(256) void k_prep(const float* __restrict__ W, const float* __restrict__ w_d1,
                                              const float* __restrict__ w_c1, const float* __restrict__ w_c2,
                                              short* __restrict__ Wf, short* __restrict__ wd1f,
                                              short* __restrict__ wc1f, short* __restrict__ wc2f) {
    int t = blockIdx.x * 256 + threadIdx.x;
    if (t < 589824) {
        int i = t & 7, lane = (t >> 3) & 63, ot = (t >> 9) & 15, kt = t >> 13;   // kt < 72
        int o = ot * 16 + (lane & 15);
        int n = (kt & 7) * 32 + (lane >> 4) * 8 + i;
        Wf[t] = f2bf(2.0f * W[o * 2304 + n * 9 + (kt >> 3)]);
    } else if (t < 589824 + 147456) {
        int t2 = t - 589824;
        int i = t2 & 7, lane = (t2 >> 3) & 63, wv = (t2 >> 9) & 3, kc = t2 >> 11; // kc < 72
        int m = wv * 16 + (lane & 15);
        int n = (kc & 7) * 32 + (lane >> 4) * 8 + i;
        wd1f[t2] = f2bf(w_d1[m * 2304 + n * 9 + (kc >> 3)]);
    } else if (t < 589824 + 147456 + 16384) {
        int t3 = t - (589824 + 147456);
        int i = t3 & 7, lane = (t3 >> 3) & 63, wv = (t3 >> 9) & 3, s = t3 >> 11;  // s < 8
        int m = wv * 16 + (lane & 15);
        int n = s * 32 + (lane >> 4) * 8 + i;
        wc1f[t3] = f2bf(w_c1[m * 256 + n]);
    } else if (t < 589824 + 147456 + 32768) {
        int t4 = t - (589824 + 147456 + 16384);
        int i = t4 & 7, lane = (t4 >> 3) & 63, ot = (t4 >> 9) & 15, s = t4 >> 13; // s < 2
        int o = ot * 16 + (lane & 15);
        int kk = s * 32 + (lane >> 4) * 8 + i;
        wc2f[t4] = f2bf(w_c2[o * 64 + kk]);
    }
}

// ---------------- prep: padded x in n-pack layout ----------------
// xT8[b][hp][np][wp][8] bf16 : hp,wp in [0,66) (borders zero), np = n>>3 (32 packs).
// idx = (((b*66+hp)*32+np)*66+wp)*8 ; np stride 528, hp stride 16896.
__global__ __launch_bounds__(256) void k_prep_xt(const float* __restrict__ x, short* __restrict__ xT8) {
    __shared__ short t[64 * 74];
    const int rw = blockIdx.x;     // 512: b = rw>>6, hr = rw&63
    const int b = rw >> 6, hr = rw & 63;
    const int tid = threadIdx.x;
    const int hp = hr + 1;
    #define XI(HP, NP, WP) ((((size_t)(b) * 66 + (HP)) * 32 + (NP)) * 66 + (WP)) * 8
    if (tid < 64) {   // zero wp borders for this row
        int np = tid & 31, wp = (tid & 32) ? 65 : 0;
        *(i32x4*)(xT8 + XI(hp, np, wp)) = i32x4{0, 0, 0, 0};
    }
    if (hr == 0) {    // zero full hp=0,65 planes for this b
        for (int i = tid; i < 2 * 32 * 66; i += 256) {
            int pl = (i >= 32 * 66) ? 65 : 0;
            int rem = (i >= 32 * 66) ? i - 32 * 66 : i;
            int np = rem / 66, wp = rem - np * 66;
            *(i32x4*)(xT8 + XI(pl, np, wp)) = i32x4{0, 0, 0, 0};
        }
    }
    const int dn = tid >> 6, w = tid & 63;
    for (int p = 0; p < 4; ++p) {
        __syncthreads();
        #pragma unroll
        for (int jj = 0; jj < 16; ++jj) {
            int n = p * 64 + dn * 16 + jj;
            t[w * 74 + dn * 16 + jj] = f2bf(x[(((size_t)(b * 256 + n) * 64) + hr) * 64 + w]);
        }
        __syncthreads();
        #pragma unroll
        for (int q = 0; q < 2; ++q) {
            int nl = q * 4 + dn;
            *(bf16x8*)(xT8 + XI(hp, p * 8 + nl, w + 1)) = *(const bf16x8*)(t + w * 74 + nl * 8);
        }
    }
    #undef XI
}

// ---------------- branch kernel (unchanged from r10) ----------------
#define BR_YD_OFF  9216
#define BR_ENT_OFF (BR_YD_OFF + 17152)
#define BR_TOTAL   (BR_ENT_OFF + 33792)   // 60160

__global__ __launch_bounds__(512, 4) void k_branch(const short* __restrict__ xT8,
        const float* __restrict__ b_c1, const float* __restrict__ b_c2,
        const float* __restrict__ b_d1, const float* __restrict__ w_d2, const float* __restrict__ b_d2,
        const short* __restrict__ wc1f, const short* __restrict__ wc2f, const short* __restrict__ wd1f,
        short* __restrict__ en, float* __restrict__ ekT) {
    extern __shared__ char smem[];
    short* yc  = (short*)smem;
    float* ydl = (float*)(smem + BR_YD_OFF);
    short* ent = (short*)(smem + BR_ENT_OFF);

    const int rw = blockIdx.x;        // 512 blocks, 64 px (one row) each
    const int b = rw >> 6, h = rw & 63;
    const int p0 = rw << 6;
    const int tid = threadIdx.x;
    const int lane = tid & 63, wave = tid >> 6;
    const int l16 = lane & 15, lg = lane >> 4;
    const int wn = wave & 3, wm = wave >> 2;   // 2 (M) x 4 (N)
    const int cm = wn * 16 + l16;
    const size_t b66h = (size_t)(b * 66 + h);
    const int wcol = wm * 32 + l16;

    #define CONV_A(DST, KC) {                                                           \
        int k9_ = (KC) >> 3;                                                            \
        int kh_ = (k9_ * 11) >> 5, kw_ = k9_ - 3 * kh_;                                 \
        const short* xa_ = xT8 + (((b66h + kh_) * 32 + ((KC) & 7) * 4 + lg) * 66        \
                                  + wcol + kw_) * 8;                                    \
        DST[0] = *(const bf16x8*)(xa_);                                                 \
        DST[1] = *(const bf16x8*)(xa_ + 128);                                           \
    }

    // ---- GEMM1
    {
        f32x4 acc[2] = {};
        const short* wp_ = wc1f + wn * 512 + lane * 8;
        const short* xg1 = xT8 + (((b66h + 1) * 32 + lg) * 66 + wcol + 1) * 8;  // + s*2112
        bf16x8 bcur = *(const bf16x8*)(wp_);
        bf16x8 a0 = *(const bf16x8*)(xg1), a1 = *(const bf16x8*)(xg1 + 128);
        #pragma unroll
        for (int s = 0; s < 8; ++s) {
            bf16x8 bc = bcur, c0 = a0, c1 = a1;
            if (s < 7) {
                bcur = *(const bf16x8*)(wp_ + (s + 1) * 2048);
                a0 = *(const bf16x8*)(xg1 + (s + 1) * 2112);
                a1 = *(const bf16x8*)(xg1 + (s + 1) * 2112 + 128);
            }
            acc[0] = __builtin_amdgcn_mfma_f32_16x16x32_bf16(c0, bc, acc[0], 0, 0, 0);
            acc[1] = __builtin_amdgcn_mfma_f32_16x16x32_bf16(c1, bc, acc[1], 0, 0, 0);
        }
        float bias = b_c1[cm];
        #pragma unroll
        for (int mt = 0; mt < 2; ++mt)
            #pragma unroll
            for (int r = 0; r < 4; ++r) {
                int px = wm * 32 + mt * 16 + lg * 4 + r;
                float v = acc[mt][r] + bias;
                yc[px * 72 + cm] = f2bf(v > 0.f ? v : 0.f);
            }
    }

    // ---- conv GEMM
    {
        f32x4 acc[2] = {};
        const short* wp_ = wd1f + wn * 512 + lane * 8;   // kc stride 2048
        bf16x8 b0 = *(const bf16x8*)(wp_);
        bf16x8 b1 = *(const bf16x8*)(wp_ + 2048);
        bf16x8 b2 = *(const bf16x8*)(wp_ + 4096);
        bf16x8 aA[2], aB[2], aC[2];
        CONV_A(aA, 0) CONV_A(aB, 1) CONV_A(aC, 2)
        for (int kc = 0; kc < 72; kc += 3) {
            {
                bf16x8 c0 = aA[0], c1 = aA[1], bc = b0;
                int cn = (kc + 3 < 72) ? kc + 3 : 71;
                CONV_A(aA, cn)
                b0 = *(const bf16x8*)(wp_ + cn * 2048);
                acc[0] = __builtin_amdgcn_mfma_f32_16x16x32_bf16(c0, bc, acc[0], 0, 0, 0);
                acc[1] = __builtin_amdgcn_mfma_f32_16x16x32_bf16(c1, bc, acc[1], 0, 0, 0);
            }
            {
                bf16x8 c0 = aB[0], c1 = aB[1], bc = b1;
                int cn = (kc + 4 < 72) ? kc + 4 : 71;
                CONV_A(aB, cn)
                b1 = *(const bf16x8*)(wp_ + cn * 2048);
                acc[0] = __builtin_amdgcn_mfma_f32_16x16x32_bf16(c0, bc, acc[0], 0, 0, 0);
                acc[1] = __builtin_amdgcn_mfma_f32_16x16x32_bf16(c1, bc, acc[1], 0, 0, 0);
            }
            {
                bf16x8 c0 = aC[0], c1 = aC[1], bc = b2;
                int cn = (kc + 5 < 72) ? kc + 5 : 71;
                CONV_A(aC, cn)
                b2 = *(const bf16x8*)(wp_ + cn * 2048);
                acc[0] = __builtin_amdgcn_mfma_f32_16x16x32_bf16(c0, bc, acc[0], 0, 0, 0);
                acc[1] = __builtin_amdgcn_mfma_f32_16x16x32_bf16(c1, bc, acc[1], 0, 0, 0);
            }
        }
        float bias = b_d1[cm];
        #pragma unroll
        for (int mt = 0; mt < 2; ++mt)
            #pragma unroll
            for (int r = 0; r < 4; ++r) {
                int px = wm * 32 + mt * 16 + lg * 4 + r;
                float v = acc[mt][r] + bias;
                ydl[px * 67 + cm] = v > 0.f ? v : 0.f;
            }
    }
    #undef CONV_A
    __syncthreads();   // yc + ydl ready

    // ---- GEMM2 ; ent = exp(-2c)
    {
        f32x4 acc[2][4] = {};
        #pragma unroll
        for (int s = 0; s < 2; ++s) {
            int k0 = s * 32;
            bf16x8 afr[2], bfr[4];
            #pragma unroll
            for (int mt = 0; mt < 2; ++mt)
                afr[mt] = *(const bf16x8*)(yc + (wm * 32 + mt * 16 + l16) * 72 + k0 + lg * 8);
            #pragma unroll
            for (int nt = 0; nt < 4; ++nt)
                bfr[nt] = *(const bf16x8*)(wc2f + s * 8192 + (wn * 4 + nt) * 512 + lane * 8);
            #pragma unroll
            for (int mt = 0; mt < 2; ++mt)
                #pragma unroll
                for (int nt = 0; nt < 4; ++nt)
                    acc[mt][nt] = __builtin_amdgcn_mfma_f32_16x16x32_bf16(afr[mt], bfr[nt], acc[mt][nt], 0, 0, 0);
        }
        #pragma unroll
        for (int nt = 0; nt < 4; ++nt) {
            int nc = wn * 64 + nt * 16 + l16;
            float bias = b_c2[nc];
            #pragma unroll
            for (int mt = 0; mt < 2; ++mt)
                #pragma unroll
                for (int r = 0; r < 4; ++r) {
                    int px = wm * 32 + mt * 16 + lg * 4 + r;
                    float cv = acc[mt][nt][r] + bias;
                    ent[px * 264 + nc] = f2bf(exp2f(NEXP2 * cv));
                }
        }
    }

    // ---- d / ekT
    for (int t = tid; t < 576; t += 512) {
        int k = t >> 6, px = t & 63;
        float sum = b_d2[k];
        const float* yr = ydl + px * 67;
        const float* wr = w_d2 + k * 64;
        #pragma unroll 8
        for (int m = 0; m < 64; ++m) sum += yr[m] * wr[m];
        ekT[(size_t)k * PTOT + p0 + px] = exp2f(NEXP2 * sum);
    }
    __syncthreads();   // ent ready

    for (int i = tid; i < 2048; i += 512) {
        int row = i >> 5, seg = i & 31;
        *(bf16x8*)(en + (size_t)(p0 + row) * 256 + seg * 8) = *(const bf16x8*)(ent + row * 264 + seg * 8);
    }
}

// ---------------- final kernel: out = (patches*attn) . W ----------------
// 512 blocks x 64 px (one row), 8 waves (1M x 8N), acc[4][2]/wave.
// z SINGLE-buffered [64][268] + ekl -> LDS 36608 B -> 2 blocks/CU, 4 waves/SIMD.
// Phase: {x(k+1) prefetch || B loads || 64 MFMA} -> barrier -> ZSTORE(k+1) (no loads) -> barrier.
// en held in regs (loaded once); all global loads have a phase of latency cover.
#define FN_ZSTR  268
#define FN_EKL   34304                   // z [64][268] bf16
#define FN_TOTAL (FN_EKL + 2304)         // + ekl [9][64] f32 = 36608

__global__ __launch_bounds__(512, 4) void k_final(const short* __restrict__ xT8,
        const short* __restrict__ Wf, const short* __restrict__ en, const float* __restrict__ ekT,
        float* __restrict__ out) {
    extern __shared__ char smem[];
    short* zb  = (short*)smem;
    float* ekl = (float*)(smem + FN_EKL);

    const int rw = blockIdx.x;            // 512 blocks
    const int b = rw >> 6, h = rw & 63;
    const int p0 = rw << 6;               // 64 px per block
    const int tid = threadIdx.x;
    const int lane = tid & 63, wave = tid >> 6;
    const int l16 = lane & 15, lg = lane >> 4;

    for (int i = tid; i < 576; i += 512)
        ekl[i] = ekT[(size_t)(i >> 6) * PTOT + p0 + (i & 63)];

    // zbuild: lane covers px = lane, n = (wave + j*8)*8 + i, j = 0..3
    const short* xb0  = xT8 + (((size_t)(b * 66 + h) * 32 + wave) * 66 + lane) * 8; // + kh*16896 + kw*8 + j*4224
    const short* enp_ = en + (size_t)(p0 + lane) * 256 + wave * 8;                  // + j*64

    bf16x8 enr[4];
    #pragma unroll
    for (int j = 0; j < 4; ++j) enr[j] = *(const bf16x8*)(enp_ + j * 64);

    bf16x8 xpre[4];
    #define XPRE(KK) {                                                                  \
        const int kh_ = (KK) / 3, kw_ = (KK) - 3 * (kh_);                               \
        const short* xr_ = xb0 + kh_ * 16896 + kw_ * 8;                                 \
        _Pragma("unroll")                                                               \
        for (int j = 0; j < 4; ++j) xpre[j] = *(const bf16x8*)(xr_ + j * 4224);         \
    }
    // ZSTORE: pure VALU + LDS writes (xpre/enr already in registers)
    #define ZSTORE(KK) {                                                                \
        float ekv = ekl[(KK) * 64 + lane];                                              \
        short* zw_ = zb + lane * FN_ZSTR + wave * 8;                                    \
        _Pragma("unroll")                                                               \
        for (int j = 0; j < 4; ++j) {                                                   \
            bf16x8 x8 = xpre[j], e8 = enr[j];                                           \
            i32x4 zz;                                                                   \
            _Pragma("unroll")                                                           \
            for (int i = 0; i < 4; ++i) {                                               \
                float q0 = __builtin_fmaf(ekv, bf2f(e8[2 * i]),     1.0f);              \
                float q1 = __builtin_fmaf(ekv, bf2f(e8[2 * i + 1]), 1.0f);              \
                zz[i] = cvt_pk_bf16(bf2f(x8[2 * i])     * __builtin_amdgcn_rcpf(q0),    \
                                    bf2f(x8[2 * i + 1]) * __builtin_amdgcn_rcpf(q1));   \
            }                                                                           \
            *(i32x4*)(zw_ + j * 64) = zz;                                               \
        }                                                                               \
    }

    XPRE(0)
    __syncthreads();               // ekl ready
    ZSTORE(0)
    __syncthreads();               // z(0) ready

    // B fragments: kt = K*8+NC at Wf + kt*8192 + ot*512 + lane*8 ; ot = wave*2 + nt
    const short* wpB0 = Wf + (wave * 2 + 0) * 512 + lane * 8;
    const short* wpB1 = Wf + (wave * 2 + 1) * 512 + lane * 8;

    f32x4 acc[4][2] = {};
    const int abase = l16 * FN_ZSTR + lg * 8;

    #define GCHUNK(NC, BC, BN, DOPREF) {                                                \
        if (DOPREF) {                                                                   \
            BN[0] = *(const bf16x8*)(wpB0 + kbf + ((NC) + 2) * 8192);                   \
            BN[1] = *(const bf16x8*)(wpB1 + kbf + ((NC) + 2) * 8192);                   \
        }                                                                               \
        bf16x8 afr[4];                                                                  \
        _Pragma("unroll")                                                               \
        for (int mt = 0; mt < 4; ++mt)                                                  \
            afr[mt] = *(const bf16x8*)(zb + abase + mt * 16 * FN_ZSTR + (NC) * 32);     \
        __builtin_amdgcn_s_setprio(1);                                                  \
        _Pragma("unroll")                                                               \
        for (int mt = 0; mt < 4; ++mt) {                                                \
            acc[mt][0] = __builtin_amdgcn_mfma_f32_16x16x32_bf16(afr[mt], BC[0], acc[mt][0], 0, 0, 0); \
            acc[mt][1] = __builtin_amdgcn_mfma_f32_16x16x32_bf16(afr[mt], BC[1], acc[mt][1], 0, 0, 0); \
        }                                                                               \
        __builtin_amdgcn_s_setprio(0);                                                  \
    }
    #define PHASE(K) {                                                                  \
        const int kbf = (K) * 65536;                                                    \
        if ((K) < 8) XPRE((K) + 1)                                                      \
        bf16x8 Ba[2], Bb[2], Bc[2];                                                     \
        Ba[0] = *(const bf16x8*)(wpB0 + kbf);                                           \
        Ba[1] = *(const bf16x8*)(wpB1 + kbf);                                           \
        Bb[0] = *(const bf16x8*)(wpB0 + kbf + 8192);                                    \
        Bb[1] = *(const bf16x8*)(wpB1 + kbf + 8192);                                    \
        GCHUNK(0, Ba, Bc, 1) GCHUNK(1, Bb, Ba, 1) GCHUNK(2, Bc, Bb, 1)                  \
        GCHUNK(3, Ba, Bc, 1) GCHUNK(4, Bb, Ba, 1) GCHUNK(5, Bc, Bb, 1)                  \
        GCHUNK(6, Ba, Bc, 0) GCHUNK(7, Bb, Ba, 0)                                       \
        __syncthreads();                                                                \
        if ((K) < 8) { ZSTORE((K) + 1) }                                                \
        __syncthreads();                                                                \
    }

    PHASE(0) PHASE(1) PHASE(2) PHASE(3) PHASE(4)
    PHASE(5) PHASE(6) PHASE(7) PHASE(8)

    #undef PHASE
    #undef GCHUNK
    #undef ZSTORE
    #undef XPRE

    // epilogue: direct coalesced stores (16B/lane, 64B runs per o-row)
    #pragma unroll
    for (int mt = 0; mt < 4; ++mt)
        #pragma unroll
        for (int nt = 0; nt < 2; ++nt) {
            int o = wave * 32 + nt * 16 + l16;
            float* d = out + (((size_t)b * 256 + o) * 64 + h) * 64 + mt * 16 + lg * 4;
            *(f32x4*)d = acc[mt][nt];
        }
}

// ---------------- launcher ----------------
extern "C" void kernel_launch(void* const* d_in, const int* in_sizes, int n_in,
                              void* d_out, int out_size, void* d_ws, size_t ws_size,
                              hipStream_t stream) {
    const float* x    = (const float*)d_in[0];
    const float* w_c1 = (const float*)d_in[1];
    const float* b_c1 = (const float*)d_in[2];
    const float* w_c2 = (const float*)d_in[3];
    const float* b_c2 = (const float*)d_in[4];
    const float* w_d1 = (const float*)d_in[5];
    const float* b_d1 = (const float*)d_in[6];
    const float* w_d2 = (const float*)d_in[7];
    const float* b_d2 = (const float*)d_in[8];
    const float* Wt   = (const float*)d_in[9];
    float* out = (float*)d_out;
    char* ws = (char*)d_ws;

    short* wc1f = (short*)(ws + WS_WC1F);
    short* wc2f = (short*)(ws + WS_WC2F);
    short* wd1f = (short*)(ws + WS_WD1F);
    short* Wf   = (short*)(ws + WS_WF);
    float* ekT  = (float*)(ws + WS_EKT);
    short* en   = (short*)(ws + WS_EN);
    short* xT8  = (short*)(ws + WS_XT);

    (void)hipFuncSetAttribute((const void*)k_branch, hipFuncAttributeMaxDynamicSharedMemorySize, BR_TOTAL);
    (void)hipFuncSetAttribute((const void*)k_final,  hipFuncAttributeMaxDynamicSharedMemorySize, FN_TOTAL);

    k_prep<<<3008, 256, 0, stream>>>(Wt, w_d1, w_c1, w_c2, Wf, wd1f, wc1f, wc2f);
    k_prep_xt<<<512, 256, 0, stream>>>(x, xT8);
    k_branch<<<512, 512, BR_TOTAL, stream>>>(xT8, b_c1, b_c2, b_d1, w_d2, b_d2, wc1f, wc2f, wd1f, en, ekT);
    k_final<<<512, 512, FN_TOTAL, stream>>>(xT8, Wf, en, ekT, out);
}

// Round 13
// 148.536 us; speedup vs baseline: 1.4514x; 1.4514x over previous
//
#include <hip/hip_runtime.h>
#include <hip/hip_bf16.h>
#include <stdint.h>

// ---------------- types / helpers ----------------
typedef __attribute__((ext_vector_type(8))) short bf16x8;
typedef __attribute__((ext_vector_type(4))) float f32x4;
typedef __attribute__((ext_vector_type(4))) int   i32x4;

#define DEV static __device__ __forceinline__

DEV float bf2f(short s) {
    unsigned u = ((unsigned)(unsigned short)s) << 16;
    return __builtin_bit_cast(float, u);
}
DEV short f2bf(float f) {  // RNE (software; prep paths)
    unsigned u = __builtin_bit_cast(unsigned, f);
    unsigned r = u + 0x7fffu + ((u >> 16) & 1u);
    return (short)(r >> 16);
}
DEV unsigned cvt_pk_bf16(float lo, float hi) {  // single HW instr
    unsigned r;
    asm("v_cvt_pk_bf16_f32 %0, %1, %2" : "=v"(r) : "v"(lo), "v"(hi));
    return r;
}
DEV void async_copy16(void* lds, const void* g) {  // DMA: lds[base + lane*16] <- g(lane)
    __builtin_amdgcn_global_load_lds((const __attribute__((address_space(1))) void*)g,
                                     (__attribute__((address_space(3))) void*)lds, 16, 0, 0);
}

// problem constants
#define PTOT 32768
#define NEXP2 (-2.885390081777927f)   // -2*log2(e)

// ws byte offsets
#define WS_WC1F 0          // wc1f: 16384 shorts
#define WS_WC2F 32768      // wc2f: 16384 shorts
#define WS_WD1F 65536      // wd1f: 147456 shorts
#define WS_WF   360448     // Wf:   589824 shorts
#define WS_EKT  1540096
#define WS_EN   2719744    // enF: 16.8 MB
#define WS_XT   19496960   // xT8: 8*66*32*66*8 bf16 = 17842176 B ; total ~37.3 MB

// ---------------- prep: fragment-major weight reorder + bf16 cast ----------------
__global__ __launch_bounds__(256) void k_prep(const float* __restrict__ W, const float* __restrict__ w_d1,
                                              const float* __restrict__ w_c1, const float* __restrict__ w_c2,
                                              short* __restrict__ Wf, short* __restrict__ wd1f,
                                              short* __restrict__ wc1f, short* __restrict__ wc2f) {
    int t = blockIdx.x * 256 + threadIdx.x;
    if (t < 589824) {
        int i = t & 7, lane = (t >> 3) & 63, ot = (t >> 9) & 15, kt = t >> 13;   // kt < 72
        int o = ot * 16 + (lane & 15);
        int n = (kt & 7) * 32 + (lane >> 4) * 8 + i;
        Wf[t] = f2bf(2.0f * W[o * 2304 + n * 9 + (kt >> 3)]);
    } else if (t < 589824 + 147456) {
        int t2 = t - 589824;
        int i = t2 & 7, lane = (t2 >> 3) & 63, wv = (t2 >> 9) & 3, kc = t2 >> 11; // kc < 72
        int m = wv * 16 + (lane & 15);
        int n = (kc & 7) * 32 + (lane >> 4) * 8 + i;
        wd1f[t2] = f2bf(w_d1[m * 2304 + n * 9 + (kc >> 3)]);
    } else if (t < 589824 + 147456 + 16384) {
        int t3 = t - (589824 + 147456);
        int i = t3 & 7, lane = (t3 >> 3) & 63, wv = (t3 >> 9) & 3, s = t3 >> 11;  // s < 8
        int m = wv * 16 + (lane & 15);
        int n = s * 32 + (lane >> 4) * 8 + i;
        wc1f[t3] = f2bf(w_c1[m * 256 + n]);
    } else if (t < 589824 + 147456 + 32768) {
        int t4 = t - (589824 + 147456 + 16384);
        int i = t4 & 7, lane = (t4 >> 3) & 63, ot = (t4 >> 9) & 15, s = t4 >> 13; // s < 2
        int o = ot * 16 + (lane & 15);
        int kk = s * 32 + (lane >> 4) * 8 + i;
        wc2f[t4] = f2bf(w_c2[o * 64 + kk]);
    }
}

// ---------------- prep: padded x in n-pack layout ----------------
// xT8[b][hp][np][wp][8] bf16 : hp,wp in [0,66) (borders zero), np = n>>3 (32 packs).
__global__ __launch_bounds__(256) void k_prep_xt(const float* __restrict__ x, short* __restrict__ xT8) {
    __shared__ short t[64 * 74];
    const int rw = blockIdx.x;     // 512: b = rw>>6, hr = rw&63
    const int b = rw >> 6, hr = rw & 63;
    const int tid = threadIdx.x;
    const int hp = hr + 1;
    #define XI(HP, NP, WP) ((((size_t)(b) * 66 + (HP)) * 32 + (NP)) * 66 + (WP)) * 8
    if (tid < 64) {   // zero wp borders for this row
        int np = tid & 31, wp = (tid & 32) ? 65 : 0;
        *(i32x4*)(xT8 + XI(hp, np, wp)) = i32x4{0, 0, 0, 0};
    }
    if (hr == 0) {    // zero full hp=0,65 planes for this b
        for (int i = tid; i < 2 * 32 * 66; i += 256) {
            int pl = (i >= 32 * 66) ? 65 : 0;
            int rem = (i >= 32 * 66) ? i - 32 * 66 : i;
            int np = rem / 66, wp = rem - np * 66;
            *(i32x4*)(xT8 + XI(pl, np, wp)) = i32x4{0, 0, 0, 0};
        }
    }
    const int dn = tid >> 6, w = tid & 63;
    for (int p = 0; p < 4; ++p) {
        __syncthreads();
        #pragma unroll
        for (int jj = 0; jj < 16; ++jj) {
            int n = p * 64 + dn * 16 + jj;
            t[w * 74 + dn * 16 + jj] = f2bf(x[(((size_t)(b * 256 + n) * 64) + hr) * 64 + w]);
        }
        __syncthreads();
        #pragma unroll
        for (int q = 0; q < 2; ++q) {
            int nl = q * 4 + dn;
            *(bf16x8*)(xT8 + XI(hp, p * 8 + nl, w + 1)) = *(const bf16x8*)(t + w * 74 + nl * 8);
        }
    }
    #undef XI
}

// ---------------- branch kernel: enF (= e^{-2c}) and ekT (= e^{-2d}) ----------------
// enF layout per 64px row-block: [8 n0c][4 n8][64 px][8] (16B lane-contiguous for k_final).
#define BR_YD_OFF  9216
#define BR_ENT_OFF (BR_YD_OFF + 17152)
#define BR_TOTAL   (BR_ENT_OFF + 33792)   // 60160

__global__ __launch_bounds__(512, 4) void k_branch(const short* __restrict__ xT8,
        const float* __restrict__ b_c1, const float* __restrict__ b_c2,
        const float* __restrict__ b_d1, const float* __restrict__ w_d2, const float* __restrict__ b_d2,
        const short* __restrict__ wc1f, const short* __restrict__ wc2f, const short* __restrict__ wd1f,
        short* __restrict__ enF, float* __restrict__ ekT) {
    extern __shared__ char smem[];
    short* yc  = (short*)smem;
    float* ydl = (float*)(smem + BR_YD_OFF);
    short* ent = (short*)(smem + BR_ENT_OFF);

    const int rw = blockIdx.x;        // 512 blocks, 64 px (one row) each
    const int b = rw >> 6, h = rw & 63;
    const int p0 = rw << 6;
    const int tid = threadIdx.x;
    const int lane = tid & 63, wave = tid >> 6;
    const int l16 = lane & 15, lg = lane >> 4;
    const int wn = wave & 3, wm = wave >> 2;   // 2 (M) x 4 (N)
    const int cm = wn * 16 + l16;
    const size_t b66h = (size_t)(b * 66 + h);
    const int wcol = wm * 32 + l16;

    #define CONV_A(DST, KC) {                                                           \
        int k9_ = (KC) >> 3;                                                            \
        int kh_ = (k9_ * 11) >> 5, kw_ = k9_ - 3 * kh_;                                 \
        const short* xa_ = xT8 + (((b66h + kh_) * 32 + ((KC) & 7) * 4 + lg) * 66        \
                                  + wcol + kw_) * 8;                                    \
        DST[0] = *(const bf16x8*)(xa_);                                                 \
        DST[1] = *(const bf16x8*)(xa_ + 128);                                           \
    }

    // ---- GEMM1: yc = relu(x . w_c1^T + b_c1)
    {
        f32x4 acc[2] = {};
        const short* wp_ = wc1f + wn * 512 + lane * 8;
        const short* xg1 = xT8 + (((b66h + 1) * 32 + lg) * 66 + wcol + 1) * 8;  // + s*2112
        bf16x8 bcur = *(const bf16x8*)(wp_);
        bf16x8 a0 = *(const bf16x8*)(xg1), a1 = *(const bf16x8*)(xg1 + 128);
        #pragma unroll
        for (int s = 0; s < 8; ++s) {
            bf16x8 bc = bcur, c0 = a0, c1 = a1;
            if (s < 7) {
                bcur = *(const bf16x8*)(wp_ + (s + 1) * 2048);
                a0 = *(const bf16x8*)(xg1 + (s + 1) * 2112);
                a1 = *(const bf16x8*)(xg1 + (s + 1) * 2112 + 128);
            }
            acc[0] = __builtin_amdgcn_mfma_f32_16x16x32_bf16(c0, bc, acc[0], 0, 0, 0);
            acc[1] = __builtin_amdgcn_mfma_f32_16x16x32_bf16(c1, bc, acc[1], 0, 0, 0);
        }
        float bias = b_c1[cm];
        #pragma unroll
        for (int mt = 0; mt < 2; ++mt)
            #pragma unroll
            for (int r = 0; r < 4; ++r) {
                int px = wm * 32 + mt * 16 + lg * 4 + r;
                float v = acc[mt][r] + bias;
                yc[px * 72 + cm] = f2bf(v > 0.f ? v : 0.f);
            }
    }

    // ---- conv GEMM: yd = relu(conv3x3 + b_d1)
    {
        f32x4 acc[2] = {};
        const short* wp_ = wd1f + wn * 512 + lane * 8;   // kc stride 2048
        bf16x8 b0 = *(const bf16x8*)(wp_);
        bf16x8 b1 = *(const bf16x8*)(wp_ + 2048);
        bf16x8 b2 = *(const bf16x8*)(wp_ + 4096);
        bf16x8 aA[2], aB[2], aC[2];
        CONV_A(aA, 0) CONV_A(aB, 1) CONV_A(aC, 2)
        for (int kc = 0; kc < 72; kc += 3) {
            {
                bf16x8 c0 = aA[0], c1 = aA[1], bc = b0;
                int cn = (kc + 3 < 72) ? kc + 3 : 71;
                CONV_A(aA, cn)
                b0 = *(const bf16x8*)(wp_ + cn * 2048);
                acc[0] = __builtin_amdgcn_mfma_f32_16x16x32_bf16(c0, bc, acc[0], 0, 0, 0);
                acc[1] = __builtin_amdgcn_mfma_f32_16x16x32_bf16(c1, bc, acc[1], 0, 0, 0);
            }
            {
                bf16x8 c0 = aB[0], c1 = aB[1], bc = b1;
                int cn = (kc + 4 < 72) ? kc + 4 : 71;
                CONV_A(aB, cn)
                b1 = *(const bf16x8*)(wp_ + cn * 2048);
                acc[0] = __builtin_amdgcn_mfma_f32_16x16x32_bf16(c0, bc, acc[0], 0, 0, 0);
                acc[1] = __builtin_amdgcn_mfma_f32_16x16x32_bf16(c1, bc, acc[1], 0, 0, 0);
            }
            {
                bf16x8 c0 = aC[0], c1 = aC[1], bc = b2;
                int cn = (kc + 5 < 72) ? kc + 5 : 71;
                CONV_A(aC, cn)
                b2 = *(const bf16x8*)(wp_ + cn * 2048);
                acc[0] = __builtin_amdgcn_mfma_f32_16x16x32_bf16(c0, bc, acc[0], 0, 0, 0);
                acc[1] = __builtin_amdgcn_mfma_f32_16x16x32_bf16(c1, bc, acc[1], 0, 0, 0);
            }
        }
        float bias = b_d1[cm];
        #pragma unroll
        for (int mt = 0; mt < 2; ++mt)
            #pragma unroll
            for (int r = 0; r < 4; ++r) {
                int px = wm * 32 + mt * 16 + lg * 4 + r;
                float v = acc[mt][r] + bias;
                ydl[px * 67 + cm] = v > 0.f ? v : 0.f;
            }
    }
    #undef CONV_A
    __syncthreads();   // yc + ydl ready

    // ---- GEMM2 ; ent = exp(-2c)
    {
        f32x4 acc[2][4] = {};
        #pragma unroll
        for (int s = 0; s < 2; ++s) {
            int k0 = s * 32;
            bf16x8 afr[2], bfr[4];
            #pragma unroll
            for (int mt = 0; mt < 2; ++mt)
                afr[mt] = *(const bf16x8*)(yc + (wm * 32 + mt * 16 + l16) * 72 + k0 + lg * 8);
            #pragma unroll
            for (int nt = 0; nt < 4; ++nt)
                bfr[nt] = *(const bf16x8*)(wc2f + s * 8192 + (wn * 4 + nt) * 512 + lane * 8);
            #pragma unroll
            for (int mt = 0; mt < 2; ++mt)
                #pragma unroll
                for (int nt = 0; nt < 4; ++nt)
                    acc[mt][nt] = __builtin_amdgcn_mfma_f32_16x16x32_bf16(afr[mt], bfr[nt], acc[mt][nt], 0, 0, 0);
        }
        #pragma unroll
        for (int nt = 0; nt < 4; ++nt) {
            int nc = wn * 64 + nt * 16 + l16;
            float bias = b_c2[nc];
            #pragma unroll
            for (int mt = 0; mt < 2; ++mt)
                #pragma unroll
                for (int r = 0; r < 4; ++r) {
                    int px = wm * 32 + mt * 16 + lg * 4 + r;
                    float cv = acc[mt][nt][r] + bias;
                    ent[px * 264 + nc] = f2bf(exp2f(NEXP2 * cv));
                }
        }
    }

    // ---- d / ekT
    for (int t = tid; t < 576; t += 512) {
        int k = t >> 6, px = t & 63;
        float sum = b_d2[k];
        const float* yr = ydl + px * 67;
        const float* wr = w_d2 + k * 64;
        #pragma unroll 8
        for (int m = 0; m < 64; ++m) sum += yr[m] * wr[m];
        ekT[(size_t)k * PTOT + p0 + px] = exp2f(NEXP2 * sum);
    }
    __syncthreads();   // ent ready

    // ---- enF store: [8 n0c][4 n8][64 px][8], lane-contiguous 16B
    for (int i = tid; i < 2048; i += 512) {
        int px = i & 63, seg = i >> 6;   // seg = n>>3, 0..31
        *(bf16x8*)(enF + (size_t)p0 * 256 + (seg >> 2) * 2048 + (seg & 3) * 512 + px * 8)
            = *(const bf16x8*)(ent + px * 264 + seg * 8);
    }
}

// ---------------- final kernel: m97-style K-loop ----------------
// 1024 blocks = 512 rows x 2 o-halves; block = 64px x 128o, 256 thr (4 waves).
// K = 2304 as 72 chunks of 32 (kc = k3*8 + nchunk). Per step (ONE barrier):
//   DMA B(kc+1)->Blds[nxt] (global_load_lds w16) || zbuild(kc+1)->z[nxt] (regs xr/er)
//   || xr/er <- (kc+2) || ds_read A/B(cur) + 8 MFMA -> barrier.
// LDS: z 2x[64][40] 10240 | Blds 2x8192 16384 | ekl 2304 = 28928 B -> 4-5 blocks/CU.
#define FN2_B     10240
#define FN2_EKL   26624
#define FN2_TOTAL 28928

__global__ __launch_bounds__(256, 4) void k_final(const short* __restrict__ xT8,
        const short* __restrict__ Wf, const short* __restrict__ enF, const float* __restrict__ ekT,
        float* __restrict__ out) {
    extern __shared__ char smem[];
    short* z0  = (short*)smem;               // [64][40]
    short* z1  = (short*)(smem + 5120);
    short* Bl0 = (short*)(smem + FN2_B);     // [8 ot][512]
    short* Bl1 = (short*)(smem + FN2_B + 8192);
    float* ekl = (float*)(smem + FN2_EKL);   // [9][64]

    const int rw = blockIdx.x;               // 1024
    const int row = rw >> 1, ohalf = rw & 1;
    const int b = row >> 6, h = row & 63;
    const int p0 = row << 6;
    const int tid = threadIdx.x;
    const int lane = tid & 63, wave = tid >> 6;   // 4 waves
    const int l16 = lane & 15, lg = lane >> 4;

    for (int i = tid; i < 576; i += 256)
        ekl[i] = ekT[(size_t)(i >> 6) * PTOT + p0 + (i & 63)];

    const size_t b66h = (size_t)(b * 66 + h);
    const short* enb = enF + (size_t)p0 * 256 + wave * 512 + lane * 8;   // + n0c*2048
    const char*  WfB = (const char*)Wf;

    #define DMA_B(KC, BUF) {                                                            \
        _Pragma("unroll")                                                               \
        for (int c = 0; c < 2; ++c) {                                                   \
            const char* g_ = WfB + (size_t)(KC) * 16384 + (ohalf * 8 + wave * 2 + c) * 1024 + lane * 16; \
            async_copy16((char*)(BUF) + (wave * 2 + c) * 1024, g_);                     \
        }                                                                               \
    }
    bf16x8 xr, er;
    #define XLOAD(KC2) {                                                                \
        int k3_ = (KC2) >> 3, c8_ = (KC2) & 7;                                          \
        int kh_ = (k3_ * 11) >> 5, kw_ = k3_ - 3 * kh_;                                 \
        xr = *(const bf16x8*)(xT8 + ((b66h + kh_) * 32 + c8_ * 4 + wave) * 528 + (lane + kw_) * 8); \
        er = *(const bf16x8*)(enb + c8_ * 2048);                                        \
    }
    #define ZBUILD(ZBUF, KC1) {                                                         \
        int k3_ = (KC1) >> 3;                                                           \
        float ekv = ekl[k3_ * 64 + lane];                                               \
        i32x4 zz;                                                                       \
        _Pragma("unroll")                                                               \
        for (int i = 0; i < 4; ++i) {                                                   \
            float q0 = __builtin_fmaf(ekv, bf2f(er[2 * i]),     1.0f);                  \
            float q1 = __builtin_fmaf(ekv, bf2f(er[2 * i + 1]), 1.0f);                  \
            zz[i] = cvt_pk_bf16(bf2f(xr[2 * i])     * __builtin_amdgcn_rcpf(q0),        \
                                bf2f(xr[2 * i + 1]) * __builtin_amdgcn_rcpf(q1));       \
        }                                                                               \
        *(i32x4*)((ZBUF) + lane * 40 + wave * 8) = zz;                                  \
    }

    // prologue
    DMA_B(0, Bl0)
    XLOAD(0)
    __syncthreads();          // ekl staged + B(0) drained
    ZBUILD(z0, 0)
    XLOAD(1)
    __syncthreads();          // z(0) visible

    f32x4 acc[4][2] = {};

    #pragma unroll 2
    for (int kc = 0; kc < 72; ++kc) {
        short* zcur = (kc & 1) ? z1 : z0;
        short* znxt = (kc & 1) ? z0 : z1;
        short* bcur = (kc & 1) ? Bl1 : Bl0;
        short* bnxt = (kc & 1) ? Bl0 : Bl1;
        if (kc < 71) {
            DMA_B(kc + 1, bnxt)       // in flight across this step; drained at barrier
            ZBUILD(znxt, kc + 1)
        }
        if (kc < 70) XLOAD(kc + 2)
        bf16x8 afr[4], bfr[2];
        #pragma unroll
        for (int mt = 0; mt < 4; ++mt)
            afr[mt] = *(const bf16x8*)(zcur + (mt * 16 + l16) * 40 + lg * 8);
        bfr[0] = *(const bf16x8*)(bcur + (wave * 2 + 0) * 512 + lane * 8);
        bfr[1] = *(const bf16x8*)(bcur + (wave * 2 + 1) * 512 + lane * 8);
        __builtin_amdgcn_s_setprio(1);
        #pragma unroll
        for (int mt = 0; mt < 4; ++mt) {
            acc[mt][0] = __builtin_amdgcn_mfma_f32_16x16x32_bf16(afr[mt], bfr[0], acc[mt][0], 0, 0, 0);
            acc[mt][1] = __builtin_amdgcn_mfma_f32_16x16x32_bf16(afr[mt], bfr[1], acc[mt][1], 0, 0, 0);
        }
        __builtin_amdgcn_s_setprio(0);
        __syncthreads();
    }
    #undef ZBUILD
    #undef XLOAD
    #undef DMA_B

    // epilogue: per (mt,nt): lanes form 16 runs of 64B (lg spans px, l16 spans o)
    const int obase = ohalf * 128;
    #pragma unroll
    for (int mt = 0; mt < 4; ++mt)
        #pragma unroll
        for (int nt = 0; nt < 2; ++nt) {
            int o = obase + (wave * 2 + nt) * 16 + l16;
            float* d = out + (((size_t)b * 256 + o) * 64 + h) * 64 + mt * 16 + lg * 4;
            *(f32x4*)d = acc[mt][nt];
        }
}

// ---------------- launcher ----------------
extern "C" void kernel_launch(void* const* d_in, const int* in_sizes, int n_in,
                              void* d_out, int out_size, void* d_ws, size_t ws_size,
                              hipStream_t stream) {
    const float* x    = (const float*)d_in[0];
    const float* w_c1 = (const float*)d_in[1];
    const float* b_c1 = (const float*)d_in[2];
    const float* w_c2 = (const float*)d_in[3];
    const float* b_c2 = (const float*)d_in[4];
    const float* w_d1 = (const float*)d_in[5];
    const float* b_d1 = (const float*)d_in[6];
    const float* w_d2 = (const float*)d_in[7];
    const float* b_d2 = (const float*)d_in[8];
    const float* Wt   = (const float*)d_in[9];
    float* out = (float*)d_out;
    char* ws = (char*)d_ws;

    short* wc1f = (short*)(ws + WS_WC1F);
    short* wc2f = (short*)(ws + WS_WC2F);
    short* wd1f = (short*)(ws + WS_WD1F);
    short* Wf   = (short*)(ws + WS_WF);
    float* ekT  = (float*)(ws + WS_EKT);
    short* enF  = (short*)(ws + WS_EN);
    short* xT8  = (short*)(ws + WS_XT);

    (void)hipFuncSetAttribute((const void*)k_branch, hipFuncAttributeMaxDynamicSharedMemorySize, BR_TOTAL);
    (void)hipFuncSetAttribute((const void*)k_final,  hipFuncAttributeMaxDynamicSharedMemorySize, FN2_TOTAL);

    k_prep<<<3008, 256, 0, stream>>>(Wt, w_d1, w_c1, w_c2, Wf, wd1f, wc1f, wc2f);
    k_prep_xt<<<512, 256, 0, stream>>>(x, xT8);
    k_branch<<<512, 512, BR_TOTAL, stream>>>(xT8, b_c1, b_c2, b_d1, w_d2, b_d2, wc1f, wc2f, wd1f, enF, ekT);
    k_final<<<1024, 256, FN2_TOTAL, stream>>>(xT8, Wf, enF, ekT, out);
}

// Round 14
// 128.344 us; speedup vs baseline: 1.6798x; 1.1573x over previous
//
#include <hip/hip_runtime.h>
#include <hip/hip_bf16.h>
#include <stdint.h>

// ---------------- types / helpers ----------------
typedef __attribute__((ext_vector_type(8))) short bf16x8;
typedef __attribute__((ext_vector_type(4))) float f32x4;
typedef __attribute__((ext_vector_type(4))) int   i32x4;

#define DEV static __device__ __forceinline__

DEV float bf2f(short s) {
    unsigned u = ((unsigned)(unsigned short)s) << 16;
    return __builtin_bit_cast(float, u);
}
DEV short f2bf(float f) {  // RNE (software; prep paths)
    unsigned u = __builtin_bit_cast(unsigned, f);
    unsigned r = u + 0x7fffu + ((u >> 16) & 1u);
    return (short)(r >> 16);
}
DEV unsigned cvt_pk_bf16(float lo, float hi) {  // single HW instr
    unsigned r;
    asm("v_cvt_pk_bf16_f32 %0, %1, %2" : "=v"(r) : "v"(lo), "v"(hi));
    return r;
}
DEV void async_copy16(void* lds, const void* g) {  // DMA: lds[base + lane*16] <- g(lane)
    __builtin_amdgcn_global_load_lds((const __attribute__((address_space(1))) void*)g,
                                     (__attribute__((address_space(3))) void*)lds, 16, 0, 0);
}

// problem constants
#define PTOT 32768
#define NEXP2 (-2.885390081777927f)   // -2*log2(e)

// ws byte offsets
#define WS_WC1F 0          // wc1f: 16384 shorts
#define WS_WC2F 32768      // wc2f: 16384 shorts
#define WS_WD1F 65536      // wd1f: 147456 shorts
#define WS_WF   360448     // Wf:   589824 shorts
#define WS_EKT  1540096
#define WS_EN   2719744    // enF: 16.8 MB
#define WS_XT   19496960   // xT8: 8*66*32*66*8 bf16 = 17842176 B ; total ~37.3 MB

// ---------------- prep: fragment-major weight reorder + bf16 cast ----------------
__global__ __launch_bounds__(256) void k_prep(const float* __restrict__ W, const float* __restrict__ w_d1,
                                              const float* __restrict__ w_c1, const float* __restrict__ w_c2,
                                              short* __restrict__ Wf, short* __restrict__ wd1f,
                                              short* __restrict__ wc1f, short* __restrict__ wc2f) {
    int t = blockIdx.x * 256 + threadIdx.x;
    if (t < 589824) {
        int i = t & 7, lane = (t >> 3) & 63, ot = (t >> 9) & 15, kt = t >> 13;   // kt < 72
        int o = ot * 16 + (lane & 15);
        int n = (kt & 7) * 32 + (lane >> 4) * 8 + i;
        Wf[t] = f2bf(2.0f * W[o * 2304 + n * 9 + (kt >> 3)]);
    } else if (t < 589824 + 147456) {
        int t2 = t - 589824;
        int i = t2 & 7, lane = (t2 >> 3) & 63, wv = (t2 >> 9) & 3, kc = t2 >> 11; // kc < 72
        int m = wv * 16 + (lane & 15);
        int n = (kc & 7) * 32 + (lane >> 4) * 8 + i;
        wd1f[t2] = f2bf(w_d1[m * 2304 + n * 9 + (kc >> 3)]);
    } else if (t < 589824 + 147456 + 16384) {
        int t3 = t - (589824 + 147456);
        int i = t3 & 7, lane = (t3 >> 3) & 63, wv = (t3 >> 9) & 3, s = t3 >> 11;  // s < 8
        int m = wv * 16 + (lane & 15);
        int n = s * 32 + (lane >> 4) * 8 + i;
        wc1f[t3] = f2bf(w_c1[m * 256 + n]);
    } else if (t < 589824 + 147456 + 32768) {
        int t4 = t - (589824 + 147456 + 16384);
        int i = t4 & 7, lane = (t4 >> 3) & 63, ot = (t4 >> 9) & 15, s = t4 >> 13; // s < 2
        int o = ot * 16 + (lane & 15);
        int kk = s * 32 + (lane >> 4) * 8 + i;
        wc2f[t4] = f2bf(w_c2[o * 64 + kk]);
    }
}

// ---------------- prep: padded x in n-pack layout ----------------
// xT8[b][hp][np][wp][8] bf16 : hp,wp in [0,66) (borders zero), np = n>>3 (32 packs).
// XCD-swizzled: XCD x writes batch b = x (matches k_branch/k_final readers).
__global__ __launch_bounds__(256) void k_prep_xt(const float* __restrict__ x, short* __restrict__ xT8) {
    __shared__ short t[64 * 74];
    const int rw = ((blockIdx.x & 7) << 6) + (blockIdx.x >> 3);   // 512: b = rw>>6, hr = rw&63
    const int b = rw >> 6, hr = rw & 63;
    const int tid = threadIdx.x;
    const int hp = hr + 1;
    #define XI(HP, NP, WP) ((((size_t)(b) * 66 + (HP)) * 32 + (NP)) * 66 + (WP)) * 8
    if (tid < 64) {   // zero wp borders for this row
        int np = tid & 31, wp = (tid & 32) ? 65 : 0;
        *(i32x4*)(xT8 + XI(hp, np, wp)) = i32x4{0, 0, 0, 0};
    }
    if (hr == 0) {    // zero full hp=0,65 planes for this b
        for (int i = tid; i < 2 * 32 * 66; i += 256) {
            int pl = (i >= 32 * 66) ? 65 : 0;
            int rem = (i >= 32 * 66) ? i - 32 * 66 : i;
            int np = rem / 66, wp = rem - np * 66;
            *(i32x4*)(xT8 + XI(pl, np, wp)) = i32x4{0, 0, 0, 0};
        }
    }
    const int dn = tid >> 6, w = tid & 63;
    for (int p = 0; p < 4; ++p) {
        __syncthreads();
        #pragma unroll
        for (int jj = 0; jj < 16; ++jj) {
            int n = p * 64 + dn * 16 + jj;
            t[w * 74 + dn * 16 + jj] = f2bf(x[(((size_t)(b * 256 + n) * 64) + hr) * 64 + w]);
        }
        __syncthreads();
        #pragma unroll
        for (int q = 0; q < 2; ++q) {
            int nl = q * 4 + dn;
            *(bf16x8*)(xT8 + XI(hp, p * 8 + nl, w + 1)) = *(const bf16x8*)(t + w * 74 + nl * 8);
        }
    }
    #undef XI
}

// ---------------- branch kernel: enF (= e^{-2c}) and ekT (= e^{-2d}) ----------------
// enF layout per 64px row-block: [8 n0c][4 n8][64 px][8] (16B lane-contiguous for k_final).
#define BR_YD_OFF  9216
#define BR_ENT_OFF (BR_YD_OFF + 17152)
#define BR_TOTAL   (BR_ENT_OFF + 33792)   // 60160

__global__ __launch_bounds__(512, 4) void k_branch(const short* __restrict__ xT8,
        const float* __restrict__ b_c1, const float* __restrict__ b_c2,
        const float* __restrict__ b_d1, const float* __restrict__ w_d2, const float* __restrict__ b_d2,
        const short* __restrict__ wc1f, const short* __restrict__ wc2f, const short* __restrict__ wd1f,
        short* __restrict__ enF, float* __restrict__ ekT) {
    extern __shared__ char smem[];
    short* yc  = (short*)smem;
    float* ydl = (float*)(smem + BR_YD_OFF);
    short* ent = (short*)(smem + BR_ENT_OFF);

    const int rw = ((blockIdx.x & 7) << 6) + (blockIdx.x >> 3);  // XCD x <- batch x
    const int b = rw >> 6, h = rw & 63;
    const int p0 = rw << 6;
    const int tid = threadIdx.x;
    const int lane = tid & 63, wave = tid >> 6;
    const int l16 = lane & 15, lg = lane >> 4;
    const int wn = wave & 3, wm = wave >> 2;   // 2 (M) x 4 (N)
    const int cm = wn * 16 + l16;
    const size_t b66h = (size_t)(b * 66 + h);
    const int wcol = wm * 32 + l16;

    #define CONV_A(DST, KC) {                                                           \
        int k9_ = (KC) >> 3;                                                            \
        int kh_ = (k9_ * 11) >> 5, kw_ = k9_ - 3 * kh_;                                 \
        const short* xa_ = xT8 + (((b66h + kh_) * 32 + ((KC) & 7) * 4 + lg) * 66        \
                                  + wcol + kw_) * 8;                                    \
        DST[0] = *(const bf16x8*)(xa_);                                                 \
        DST[1] = *(const bf16x8*)(xa_ + 128);                                           \
    }

    // ---- GEMM1: yc = relu(x . w_c1^T + b_c1)
    {
        f32x4 acc[2] = {};
        const short* wp_ = wc1f + wn * 512 + lane * 8;
        const short* xg1 = xT8 + (((b66h + 1) * 32 + lg) * 66 + wcol + 1) * 8;  // + s*2112
        bf16x8 bcur = *(const bf16x8*)(wp_);
        bf16x8 a0 = *(const bf16x8*)(xg1), a1 = *(const bf16x8*)(xg1 + 128);
        #pragma unroll
        for (int s = 0; s < 8; ++s) {
            bf16x8 bc = bcur, c0 = a0, c1 = a1;
            if (s < 7) {
                bcur = *(const bf16x8*)(wp_ + (s + 1) * 2048);
                a0 = *(const bf16x8*)(xg1 + (s + 1) * 2112);
                a1 = *(const bf16x8*)(xg1 + (s + 1) * 2112 + 128);
            }
            acc[0] = __builtin_amdgcn_mfma_f32_16x16x32_bf16(c0, bc, acc[0], 0, 0, 0);
            acc[1] = __builtin_amdgcn_mfma_f32_16x16x32_bf16(c1, bc, acc[1], 0, 0, 0);
        }
        float bias = b_c1[cm];
        #pragma unroll
        for (int mt = 0; mt < 2; ++mt)
            #pragma unroll
            for (int r = 0; r < 4; ++r) {
                int px = wm * 32 + mt * 16 + lg * 4 + r;
                float v = acc[mt][r] + bias;
                yc[px * 72 + cm] = f2bf(v > 0.f ? v : 0.f);
            }
    }

    // ---- conv GEMM: yd = relu(conv3x3 + b_d1)
    {
        f32x4 acc[2] = {};
        const short* wp_ = wd1f + wn * 512 + lane * 8;   // kc stride 2048
        bf16x8 b0 = *(const bf16x8*)(wp_);
        bf16x8 b1 = *(const bf16x8*)(wp_ + 2048);
        bf16x8 b2 = *(const bf16x8*)(wp_ + 4096);
        bf16x8 aA[2], aB[2], aC[2];
        CONV_A(aA, 0) CONV_A(aB, 1) CONV_A(aC, 2)
        for (int kc = 0; kc < 72; kc += 3) {
            {
                bf16x8 c0 = aA[0], c1 = aA[1], bc = b0;
                int cn = (kc + 3 < 72) ? kc + 3 : 71;
                CONV_A(aA, cn)
                b0 = *(const bf16x8*)(wp_ + cn * 2048);
                acc[0] = __builtin_amdgcn_mfma_f32_16x16x32_bf16(c0, bc, acc[0], 0, 0, 0);
                acc[1] = __builtin_amdgcn_mfma_f32_16x16x32_bf16(c1, bc, acc[1], 0, 0, 0);
            }
            {
                bf16x8 c0 = aB[0], c1 = aB[1], bc = b1;
                int cn = (kc + 4 < 72) ? kc + 4 : 71;
                CONV_A(aB, cn)
                b1 = *(const bf16x8*)(wp_ + cn * 2048);
                acc[0] = __builtin_amdgcn_mfma_f32_16x16x32_bf16(c0, bc, acc[0], 0, 0, 0);
                acc[1] = __builtin_amdgcn_mfma_f32_16x16x32_bf16(c1, bc, acc[1], 0, 0, 0);
            }
            {
                bf16x8 c0 = aC[0], c1 = aC[1], bc = b2;
                int cn = (kc + 5 < 72) ? kc + 5 : 71;
                CONV_A(aC, cn)
                b2 = *(const bf16x8*)(wp_ + cn * 2048);
                acc[0] = __builtin_amdgcn_mfma_f32_16x16x32_bf16(c0, bc, acc[0], 0, 0, 0);
                acc[1] = __builtin_amdgcn_mfma_f32_16x16x32_bf16(c1, bc, acc[1], 0, 0, 0);
            }
        }
        float bias = b_d1[cm];
        #pragma unroll
        for (int mt = 0; mt < 2; ++mt)
            #pragma unroll
            for (int r = 0; r < 4; ++r) {
                int px = wm * 32 + mt * 16 + lg * 4 + r;
                float v = acc[mt][r] + bias;
                ydl[px * 67 + cm] = v > 0.f ? v : 0.f;
            }
    }
    #undef CONV_A
    __syncthreads();   // yc + ydl ready

    // ---- GEMM2 ; ent = exp(-2c)
    {
        f32x4 acc[2][4] = {};
        #pragma unroll
        for (int s = 0; s < 2; ++s) {
            int k0 = s * 32;
            bf16x8 afr[2], bfr[4];
            #pragma unroll
            for (int mt = 0; mt < 2; ++mt)
                afr[mt] = *(const bf16x8*)(yc + (wm * 32 + mt * 16 + l16) * 72 + k0 + lg * 8);
            #pragma unroll
            for (int nt = 0; nt < 4; ++nt)
                bfr[nt] = *(const bf16x8*)(wc2f + s * 8192 + (wn * 4 + nt) * 512 + lane * 8);
            #pragma unroll
            for (int mt = 0; mt < 2; ++mt)
                #pragma unroll
                for (int nt = 0; nt < 4; ++nt)
                    acc[mt][nt] = __builtin_amdgcn_mfma_f32_16x16x32_bf16(afr[mt], bfr[nt], acc[mt][nt], 0, 0, 0);
        }
        #pragma unroll
        for (int nt = 0; nt < 4; ++nt) {
            int nc = wn * 64 + nt * 16 + l16;
            float bias = b_c2[nc];
            #pragma unroll
            for (int mt = 0; mt < 2; ++mt)
                #pragma unroll
                for (int r = 0; r < 4; ++r) {
                    int px = wm * 32 + mt * 16 + lg * 4 + r;
                    float cv = acc[mt][nt][r] + bias;
                    ent[px * 264 + nc] = f2bf(exp2f(NEXP2 * cv));
                }
        }
    }

    // ---- d / ekT
    for (int t = tid; t < 576; t += 512) {
        int k = t >> 6, px = t & 63;
        float sum = b_d2[k];
        const float* yr = ydl + px * 67;
        const float* wr = w_d2 + k * 64;
        #pragma unroll 8
        for (int m = 0; m < 64; ++m) sum += yr[m] * wr[m];
        ekT[(size_t)k * PTOT + p0 + px] = exp2f(NEXP2 * sum);
    }
    __syncthreads();   // ent ready

    // ---- enF store: [8 n0c][4 n8][64 px][8], lane-contiguous 16B
    for (int i = tid; i < 2048; i += 512) {
        int px = i & 63, seg = i >> 6;   // seg = n>>3, 0..31
        *(bf16x8*)(enF + (size_t)p0 * 256 + (seg >> 2) * 2048 + (seg & 3) * 512 + px * 8)
            = *(const bf16x8*)(ent + px * 264 + seg * 8);
    }
}

// ---------------- final kernel: m97-style K-loop ----------------
// 1024 blocks = 512 rows x 2 o-halves, XCD-swizzled so XCD x owns batch x
// (rows 64x..64x+63, both o-halves adjacent -> x/en windows shared in 4MB L2).
#define FN2_B     10240
#define FN2_EKL   26624
#define FN2_TOTAL 28928

__global__ __launch_bounds__(256, 4) void k_final(const short* __restrict__ xT8,
        const short* __restrict__ Wf, const short* __restrict__ enF, const float* __restrict__ ekT,
        float* __restrict__ out) {
    extern __shared__ char smem[];
    short* z0  = (short*)smem;               // [64][40]
    short* z1  = (short*)(smem + 5120);
    short* Bl0 = (short*)(smem + FN2_B);     // [8 ot][512]
    short* Bl1 = (short*)(smem + FN2_B + 8192);
    float* ekl = (float*)(smem + FN2_EKL);   // [9][64]

    const int rw = ((blockIdx.x & 7) << 7) + (blockIdx.x >> 3);  // 1024, XCD-chunked
    const int row = rw >> 1, ohalf = rw & 1;
    const int b = row >> 6, h = row & 63;
    const int p0 = row << 6;
    const int tid = threadIdx.x;
    const int lane = tid & 63, wave = tid >> 6;   // 4 waves
    const int l16 = lane & 15, lg = lane >> 4;

    for (int i = tid; i < 576; i += 256)
        ekl[i] = ekT[(size_t)(i >> 6) * PTOT + p0 + (i & 63)];

    const size_t b66h = (size_t)(b * 66 + h);
    const short* enb = enF + (size_t)p0 * 256 + wave * 512 + lane * 8;   // + n0c*2048
    const char*  WfB = (const char*)Wf;

    #define DMA_B(KC, BUF) {                                                            \
        _Pragma("unroll")                                                               \
        for (int c = 0; c < 2; ++c) {                                                   \
            const char* g_ = WfB + (size_t)(KC) * 16384 + (ohalf * 8 + wave * 2 + c) * 1024 + lane * 16; \
            async_copy16((char*)(BUF) + (wave * 2 + c) * 1024, g_);                     \
        }                                                                               \
    }
    bf16x8 xr, er;
    #define XLOAD(KC2) {                                                                \
        int k3_ = (KC2) >> 3, c8_ = (KC2) & 7;                                          \
        int kh_ = (k3_ * 11) >> 5, kw_ = k3_ - 3 * kh_;                                 \
        xr = *(const bf16x8*)(xT8 + ((b66h + kh_) * 32 + c8_ * 4 + wave) * 528 + (lane + kw_) * 8); \
        er = *(const bf16x8*)(enb + c8_ * 2048);                                        \
    }
    #define ZBUILD(ZBUF, KC1) {                                                         \
        int k3_ = (KC1) >> 3;                                                           \
        float ekv = ekl[k3_ * 64 + lane];                                               \
        i32x4 zz;                                                                       \
        _Pragma("unroll")                                                               \
        for (int i = 0; i < 4; ++i) {                                                   \
            float q0 = __builtin_fmaf(ekv, bf2f(er[2 * i]),     1.0f);                  \
            float q1 = __builtin_fmaf(ekv, bf2f(er[2 * i + 1]), 1.0f);                  \
            zz[i] = cvt_pk_bf16(bf2f(xr[2 * i])     * __builtin_amdgcn_rcpf(q0),        \
                                bf2f(xr[2 * i + 1]) * __builtin_amdgcn_rcpf(q1));       \
        }                                                                               \
        *(i32x4*)((ZBUF) + lane * 40 + wave * 8) = zz;                                  \
    }

    // prologue
    DMA_B(0, Bl0)
    XLOAD(0)
    __syncthreads();          // ekl staged + B(0) drained
    ZBUILD(z0, 0)
    XLOAD(1)
    __syncthreads();          // z(0) visible

    f32x4 acc[4][2] = {};

    #pragma unroll 2
    for (int kc = 0; kc < 72; ++kc) {
        short* zcur = (kc & 1) ? z1 : z0;
        short* znxt = (kc & 1) ? z0 : z1;
        short* bcur = (kc & 1) ? Bl1 : Bl0;
        short* bnxt = (kc & 1) ? Bl0 : Bl1;
        if (kc < 71) {
            DMA_B(kc + 1, bnxt)       // in flight across this step; drained at barrier
            ZBUILD(znxt, kc + 1)
        }
        if (kc < 70) XLOAD(kc + 2)
        bf16x8 afr[4], bfr[2];
        #pragma unroll
        for (int mt = 0; mt < 4; ++mt)
            afr[mt] = *(const bf16x8*)(zcur + (mt * 16 + l16) * 40 + lg * 8);
        bfr[0] = *(const bf16x8*)(bcur + (wave * 2 + 0) * 512 + lane * 8);
        bfr[1] = *(const bf16x8*)(bcur + (wave * 2 + 1) * 512 + lane * 8);
        __builtin_amdgcn_s_setprio(1);
        #pragma unroll
        for (int mt = 0; mt < 4; ++mt) {
            acc[mt][0] = __builtin_amdgcn_mfma_f32_16x16x32_bf16(afr[mt], bfr[0], acc[mt][0], 0, 0, 0);
            acc[mt][1] = __builtin_amdgcn_mfma_f32_16x16x32_bf16(afr[mt], bfr[1], acc[mt][1], 0, 0, 0);
        }
        __builtin_amdgcn_s_setprio(0);
        __syncthreads();
    }
    #undef ZBUILD
    #undef XLOAD
    #undef DMA_B

    // epilogue: per (mt,nt): lanes form 16 runs of 64B (lg spans px, l16 spans o)
    const int obase = ohalf * 128;
    #pragma unroll
    for (int mt = 0; mt < 4; ++mt)
        #pragma unroll
        for (int nt = 0; nt < 2; ++nt) {
            int o = obase + (wave * 2 + nt) * 16 + l16;
            float* d = out + (((size_t)b * 256 + o) * 64 + h) * 64 + mt * 16 + lg * 4;
            *(f32x4*)d = acc[mt][nt];
        }
}

// ---------------- launcher ----------------
extern "C" void kernel_launch(void* const* d_in, const int* in_sizes, int n_in,
                              void* d_out, int out_size, void* d_ws, size_t ws_size,
                              hipStream_t stream) {
    const float* x    = (const float*)d_in[0];
    const float* w_c1 = (const float*)d_in[1];
    const float* b_c1 = (const float*)d_in[2];
    const float* w_c2 = (const float*)d_in[3];
    const float* b_c2 = (const float*)d_in[4];
    const float* w_d1 = (const float*)d_in[5];
    const float* b_d1 = (const float*)d_in[6];
    const float* w_d2 = (const float*)d_in[7];
    const float* b_d2 = (const float*)d_in[8];
    const float* Wt   = (const float*)d_in[9];
    float* out = (float*)d_out;
    char* ws = (char*)d_ws;

    short* wc1f = (short*)(ws + WS_WC1F);
    short* wc2f = (short*)(ws + WS_WC2F);
    short* wd1f = (short*)(ws + WS_WD1F);
    short* Wf   = (short*)(ws + WS_WF);
    float* ekT  = (float*)(ws + WS_EKT);
    short* enF  = (short*)(ws + WS_EN);
    short* xT8  = (short*)(ws + WS_XT);

    (void)hipFuncSetAttribute((const void*)k_branch, hipFuncAttributeMaxDynamicSharedMemorySize, BR_TOTAL);
    (void)hipFuncSetAttribute((const void*)k_final,  hipFuncAttributeMaxDynamicSharedMemorySize, FN2_TOTAL);

    k_prep<<<3008, 256, 0, stream>>>(Wt, w_d1, w_c1, w_c2, Wf, wd1f, wc1f, wc2f);
    k_prep_xt<<<512, 256, 0, stream>>>(x, xT8);
    k_branch<<<512, 512, BR_TOTAL, stream>>>(xT8, b_c1, b_c2, b_d1, w_d2, b_d2, wc1f, wc2f, wd1f, enF, ekT);
    k_final<<<1024, 256, FN2_TOTAL, stream>>>(xT8, Wf, enF, ekT, out);
}

// Round 15
// 125.365 us; speedup vs baseline: 1.7197x; 1.0238x over previous
//
#include <hip/hip_runtime.h>
#include <hip/hip_bf16.h>
#include <stdint.h>

// ---------------- types / helpers ----------------
typedef __attribute__((ext_vector_type(8))) short bf16x8;
typedef __attribute__((ext_vector_type(4))) float f32x4;
typedef __attribute__((ext_vector_type(4))) int   i32x4;

#define DEV static __device__ __forceinline__

DEV float bf2f(short s) {
    unsigned u = ((unsigned)(unsigned short)s) << 16;
    return __builtin_bit_cast(float, u);
}
DEV short f2bf(float f) {  // RNE (software; prep paths)
    unsigned u = __builtin_bit_cast(unsigned, f);
    unsigned r = u + 0x7fffu + ((u >> 16) & 1u);
    return (short)(r >> 16);
}
DEV unsigned cvt_pk_bf16(float lo, float hi) {  // single HW instr
    unsigned r;
    asm("v_cvt_pk_bf16_f32 %0, %1, %2" : "=v"(r) : "v"(lo), "v"(hi));
    return r;
}
DEV void async_copy16(void* lds, const void* g) {  // DMA: lds[base + lane*16] <- g(lane)
    __builtin_amdgcn_global_load_lds((const __attribute__((address_space(1))) void*)g,
                                     (__attribute__((address_space(3))) void*)lds, 16, 0, 0);
}

// problem constants
#define PTOT 32768
#define NEXP2 (-2.885390081777927f)   // -2*log2(e)

// ws byte offsets
#define WS_WC1F 0          // wc1f: 16384 shorts
#define WS_WC2F 32768      // wc2f: 16384 shorts
#define WS_WD1F 65536      // wd1f: 147456 shorts
#define WS_WF   360448     // Wf:   589824 shorts
#define WS_EKT  1540096
#define WS_EN   2719744    // enF: 16.8 MB
#define WS_XT   19496960   // xT8: 8*66*32*66*8 bf16 = 17842176 B ; total ~37.3 MB

// ---------------- prep: fragment-major weight reorder + bf16 cast ----------------
__global__ __launch_bounds__(256) void k_prep(const float* __restrict__ W, const float* __restrict__ w_d1,
                                              const float* __restrict__ w_c1, const float* __restrict__ w_c2,
                                              short* __restrict__ Wf, short* __restrict__ wd1f,
                                              short* __restrict__ wc1f, short* __restrict__ wc2f) {
    int t = blockIdx.x * 256 + threadIdx.x;
    if (t < 589824) {
        int i = t & 7, lane = (t >> 3) & 63, ot = (t >> 9) & 15, kt = t >> 13;   // kt < 72
        int o = ot * 16 + (lane & 15);
        int n = (kt & 7) * 32 + (lane >> 4) * 8 + i;
        Wf[t] = f2bf(2.0f * W[o * 2304 + n * 9 + (kt >> 3)]);
    } else if (t < 589824 + 147456) {
        int t2 = t - 589824;
        int i = t2 & 7, lane = (t2 >> 3) & 63, wv = (t2 >> 9) & 3, kc = t2 >> 11; // kc < 72
        int m = wv * 16 + (lane & 15);
        int n = (kc & 7) * 32 + (lane >> 4) * 8 + i;
        wd1f[t2] = f2bf(w_d1[m * 2304 + n * 9 + (kc >> 3)]);
    } else if (t < 589824 + 147456 + 16384) {
        int t3 = t - (589824 + 147456);
        int i = t3 & 7, lane = (t3 >> 3) & 63, wv = (t3 >> 9) & 3, s = t3 >> 11;  // s < 8
        int m = wv * 16 + (lane & 15);
        int n = s * 32 + (lane >> 4) * 8 + i;
        wc1f[t3] = f2bf(w_c1[m * 256 + n]);
    } else if (t < 589824 + 147456 + 32768) {
        int t4 = t - (589824 + 147456 + 16384);
        int i = t4 & 7, lane = (t4 >> 3) & 63, ot = (t4 >> 9) & 15, s = t4 >> 13; // s < 2
        int o = ot * 16 + (lane & 15);
        int kk = s * 32 + (lane >> 4) * 8 + i;
        wc2f[t4] = f2bf(w_c2[o * 64 + kk]);
    }
}

// ---------------- prep: padded x in n-pack layout ----------------
// xT8[b][hp][np][wp][8] bf16 : hp,wp in [0,66) (borders zero), np = n>>3 (32 packs).
// XCD-swizzled: XCD x writes batch b = x (matches k_branch/k_final readers).
__global__ __launch_bounds__(256) void k_prep_xt(const float* __restrict__ x, short* __restrict__ xT8) {
    __shared__ short t[64 * 74];
    const int rw = ((blockIdx.x & 7) << 6) + (blockIdx.x >> 3);   // 512: b = rw>>6, hr = rw&63
    const int b = rw >> 6, hr = rw & 63;
    const int tid = threadIdx.x;
    const int hp = hr + 1;
    #define XI(HP, NP, WP) ((((size_t)(b) * 66 + (HP)) * 32 + (NP)) * 66 + (WP)) * 8
    if (tid < 64) {   // zero wp borders for this row
        int np = tid & 31, wp = (tid & 32) ? 65 : 0;
        *(i32x4*)(xT8 + XI(hp, np, wp)) = i32x4{0, 0, 0, 0};
    }
    if (hr == 0) {    // zero full hp=0,65 planes for this b
        for (int i = tid; i < 2 * 32 * 66; i += 256) {
            int pl = (i >= 32 * 66) ? 65 : 0;
            int rem = (i >= 32 * 66) ? i - 32 * 66 : i;
            int np = rem / 66, wp = rem - np * 66;
            *(i32x4*)(xT8 + XI(pl, np, wp)) = i32x4{0, 0, 0, 0};
        }
    }
    const int dn = tid >> 6, w = tid & 63;
    for (int p = 0; p < 4; ++p) {
        __syncthreads();
        #pragma unroll
        for (int jj = 0; jj < 16; ++jj) {
            int n = p * 64 + dn * 16 + jj;
            t[w * 74 + dn * 16 + jj] = f2bf(x[(((size_t)(b * 256 + n) * 64) + hr) * 64 + w]);
        }
        __syncthreads();
        #pragma unroll
        for (int q = 0; q < 2; ++q) {
            int nl = q * 4 + dn;
            *(bf16x8*)(xT8 + XI(hp, p * 8 + nl, w + 1)) = *(const bf16x8*)(t + w * 74 + nl * 8);
        }
    }
    #undef XI
}

// ---------------- branch kernel: enF (= e^{-2c}) and ekT (= e^{-2d}) ----------------
// enF layout per 64px row-block: [8 n0c][4 n8][64 px][8] (16B lane-contiguous for k_final).
#define BR_YD_OFF  9216
#define BR_ENT_OFF (BR_YD_OFF + 17152)
#define BR_TOTAL   (BR_ENT_OFF + 33792)   // 60160

__global__ __launch_bounds__(512, 4) void k_branch(const short* __restrict__ xT8,
        const float* __restrict__ b_c1, const float* __restrict__ b_c2,
        const float* __restrict__ b_d1, const float* __restrict__ w_d2, const float* __restrict__ b_d2,
        const short* __restrict__ wc1f, const short* __restrict__ wc2f, const short* __restrict__ wd1f,
        short* __restrict__ enF, float* __restrict__ ekT) {
    extern __shared__ char smem[];
    short* yc  = (short*)smem;
    float* ydl = (float*)(smem + BR_YD_OFF);
    short* ent = (short*)(smem + BR_ENT_OFF);

    const int rw = ((blockIdx.x & 7) << 6) + (blockIdx.x >> 3);  // XCD x <- batch x
    const int b = rw >> 6, h = rw & 63;
    const int p0 = rw << 6;
    const int tid = threadIdx.x;
    const int lane = tid & 63, wave = tid >> 6;
    const int l16 = lane & 15, lg = lane >> 4;
    const int wn = wave & 3, wm = wave >> 2;   // 2 (M) x 4 (N)
    const int cm = wn * 16 + l16;
    const size_t b66h = (size_t)(b * 66 + h);
    const int wcol = wm * 32 + l16;

    #define CONV_A(DST, KC) {                                                           \
        int k9_ = (KC) >> 3;                                                            \
        int kh_ = (k9_ * 11) >> 5, kw_ = k9_ - 3 * kh_;                                 \
        const short* xa_ = xT8 + (((b66h + kh_) * 32 + ((KC) & 7) * 4 + lg) * 66        \
                                  + wcol + kw_) * 8;                                    \
        DST[0] = *(const bf16x8*)(xa_);                                                 \
        DST[1] = *(const bf16x8*)(xa_ + 128);                                           \
    }

    // ---- GEMM1: yc = relu(x . w_c1^T + b_c1)
    {
        f32x4 acc[2] = {};
        const short* wp_ = wc1f + wn * 512 + lane * 8;
        const short* xg1 = xT8 + (((b66h + 1) * 32 + lg) * 66 + wcol + 1) * 8;  // + s*2112
        bf16x8 bcur = *(const bf16x8*)(wp_);
        bf16x8 a0 = *(const bf16x8*)(xg1), a1 = *(const bf16x8*)(xg1 + 128);
        #pragma unroll
        for (int s = 0; s < 8; ++s) {
            bf16x8 bc = bcur, c0 = a0, c1 = a1;
            if (s < 7) {
                bcur = *(const bf16x8*)(wp_ + (s + 1) * 2048);
                a0 = *(const bf16x8*)(xg1 + (s + 1) * 2112);
                a1 = *(const bf16x8*)(xg1 + (s + 1) * 2112 + 128);
            }
            acc[0] = __builtin_amdgcn_mfma_f32_16x16x32_bf16(c0, bc, acc[0], 0, 0, 0);
            acc[1] = __builtin_amdgcn_mfma_f32_16x16x32_bf16(c1, bc, acc[1], 0, 0, 0);
        }
        float bias = b_c1[cm];
        #pragma unroll
        for (int mt = 0; mt < 2; ++mt)
            #pragma unroll
            for (int r = 0; r < 4; ++r) {
                int px = wm * 32 + mt * 16 + lg * 4 + r;
                float v = acc[mt][r] + bias;
                yc[px * 72 + cm] = f2bf(v > 0.f ? v : 0.f);
            }
    }

    // ---- conv GEMM: yd = relu(conv3x3 + b_d1)
    {
        f32x4 acc[2] = {};
        const short* wp_ = wd1f + wn * 512 + lane * 8;   // kc stride 2048
        bf16x8 b0 = *(const bf16x8*)(wp_);
        bf16x8 b1 = *(const bf16x8*)(wp_ + 2048);
        bf16x8 b2 = *(const bf16x8*)(wp_ + 4096);
        bf16x8 aA[2], aB[2], aC[2];
        CONV_A(aA, 0) CONV_A(aB, 1) CONV_A(aC, 2)
        for (int kc = 0; kc < 72; kc += 3) {
            {
                bf16x8 c0 = aA[0], c1 = aA[1], bc = b0;
                int cn = (kc + 3 < 72) ? kc + 3 : 71;
                CONV_A(aA, cn)
                b0 = *(const bf16x8*)(wp_ + cn * 2048);
                acc[0] = __builtin_amdgcn_mfma_f32_16x16x32_bf16(c0, bc, acc[0], 0, 0, 0);
                acc[1] = __builtin_amdgcn_mfma_f32_16x16x32_bf16(c1, bc, acc[1], 0, 0, 0);
            }
            {
                bf16x8 c0 = aB[0], c1 = aB[1], bc = b1;
                int cn = (kc + 4 < 72) ? kc + 4 : 71;
                CONV_A(aB, cn)
                b1 = *(const bf16x8*)(wp_ + cn * 2048);
                acc[0] = __builtin_amdgcn_mfma_f32_16x16x32_bf16(c0, bc, acc[0], 0, 0, 0);
                acc[1] = __builtin_amdgcn_mfma_f32_16x16x32_bf16(c1, bc, acc[1], 0, 0, 0);
            }
            {
                bf16x8 c0 = aC[0], c1 = aC[1], bc = b2;
                int cn = (kc + 5 < 72) ? kc + 5 : 71;
                CONV_A(aC, cn)
                b2 = *(const bf16x8*)(wp_ + cn * 2048);
                acc[0] = __builtin_amdgcn_mfma_f32_16x16x32_bf16(c0, bc, acc[0], 0, 0, 0);
                acc[1] = __builtin_amdgcn_mfma_f32_16x16x32_bf16(c1, bc, acc[1], 0, 0, 0);
            }
        }
        float bias = b_d1[cm];
        #pragma unroll
        for (int mt = 0; mt < 2; ++mt)
            #pragma unroll
            for (int r = 0; r < 4; ++r) {
                int px = wm * 32 + mt * 16 + lg * 4 + r;
                float v = acc[mt][r] + bias;
                ydl[px * 67 + cm] = v > 0.f ? v : 0.f;
            }
    }
    #undef CONV_A
    __syncthreads();   // yc + ydl ready

    // ---- GEMM2 ; ent = exp(-2c)
    {
        f32x4 acc[2][4] = {};
        #pragma unroll
        for (int s = 0; s < 2; ++s) {
            int k0 = s * 32;
            bf16x8 afr[2], bfr[4];
            #pragma unroll
            for (int mt = 0; mt < 2; ++mt)
                afr[mt] = *(const bf16x8*)(yc + (wm * 32 + mt * 16 + l16) * 72 + k0 + lg * 8);
            #pragma unroll
            for (int nt = 0; nt < 4; ++nt)
                bfr[nt] = *(const bf16x8*)(wc2f + s * 8192 + (wn * 4 + nt) * 512 + lane * 8);
            #pragma unroll
            for (int mt = 0; mt < 2; ++mt)
                #pragma unroll
                for (int nt = 0; nt < 4; ++nt)
                    acc[mt][nt] = __builtin_amdgcn_mfma_f32_16x16x32_bf16(afr[mt], bfr[nt], acc[mt][nt], 0, 0, 0);
        }
        #pragma unroll
        for (int nt = 0; nt < 4; ++nt) {
            int nc = wn * 64 + nt * 16 + l16;
            float bias = b_c2[nc];
            #pragma unroll
            for (int mt = 0; mt < 2; ++mt)
                #pragma unroll
                for (int r = 0; r < 4; ++r) {
                    int px = wm * 32 + mt * 16 + lg * 4 + r;
                    float cv = acc[mt][nt][r] + bias;
                    ent[px * 264 + nc] = f2bf(exp2f(NEXP2 * cv));
                }
        }
    }

    // ---- d / ekT
    for (int t = tid; t < 576; t += 512) {
        int k = t >> 6, px = t & 63;
        float sum = b_d2[k];
        const float* yr = ydl + px * 67;
        const float* wr = w_d2 + k * 64;
        #pragma unroll 8
        for (int m = 0; m < 64; ++m) sum += yr[m] * wr[m];
        ekT[(size_t)k * PTOT + p0 + px] = exp2f(NEXP2 * sum);
    }
    __syncthreads();   // ent ready

    // ---- enF store: [8 n0c][4 n8][64 px][8], lane-contiguous 16B
    for (int i = tid; i < 2048; i += 512) {
        int px = i & 63, seg = i >> 6;   // seg = n>>3, 0..31
        *(bf16x8*)(enF + (size_t)p0 * 256 + (seg >> 2) * 2048 + (seg & 3) * 512 + px * 8)
            = *(const bf16x8*)(ent + px * 264 + seg * 8);
    }
}

// ---------------- final kernel: merged-o m97-style K-loop ----------------
// 512 blocks (one per row, XCD-swizzled) x (64px x 256o), 256 thr (4 waves), acc[4][4].
// zF fragment-major [mt=4][lane][8]: wave w builds quadrant w -> sequential 1KB writes;
// afr/bfr reads are base + lane*16B (BW-optimal LDS). One barrier per K-step.
// LDS: zF 2x4096 | B 2x16384 | ekl 2304 = 43264 B -> 3 blocks/CU.
#define FN3_Z1    4096
#define FN3_B0    8192
#define FN3_B1    24576
#define FN3_EKL   40960
#define FN3_TOTAL 43264

__global__ __launch_bounds__(256, 3) void k_final(const short* __restrict__ xT8,
        const short* __restrict__ Wf, const short* __restrict__ enF, const float* __restrict__ ekT,
        float* __restrict__ out) {
    extern __shared__ char smem[];
    short* z0  = (short*)smem;                 // [4][64][8]
    short* z1  = (short*)(smem + FN3_Z1);
    short* Bl0 = (short*)(smem + FN3_B0);      // [16 ot][512]
    short* Bl1 = (short*)(smem + FN3_B1);
    float* ekl = (float*)(smem + FN3_EKL);     // [9][64]

    const int rw = ((blockIdx.x & 7) << 6) + (blockIdx.x >> 3);  // 512, XCD-chunked
    const int b = rw >> 6, h = rw & 63;
    const int p0 = rw << 6;
    const int tid = threadIdx.x;
    const int lane = tid & 63, wave = tid >> 6;   // 4 waves
    const int l16 = lane & 15, lg = lane >> 4;

    for (int i = tid; i < 576; i += 256)
        ekl[i] = ekT[(size_t)(i >> 6) * PTOT + p0 + (i & 63)];

    const size_t b66h = (size_t)(b * 66 + h);
    // zbuild thread (wave, lane): px = wave*16 + (lane&15), n-slot = (lane>>4)
    const int zpx = wave * 16 + l16;
    const short* xb0  = xT8 + ((b66h * 32 + lg) * 66 + zpx) * 8;          // + (kh*32 + c8*4)*528 + kw*8
    const short* enb  = enF + (size_t)p0 * 256 + lg * 512 + zpx * 8;      // + c8*2048
    const char*  WfB  = (const char*)Wf;

    #define DMA_B(KC, BUF) {                                                            \
        _Pragma("unroll")                                                               \
        for (int c = 0; c < 4; ++c) {                                                   \
            const char* g_ = WfB + (size_t)(KC) * 16384 + (wave * 4 + c) * 1024 + lane * 16; \
            async_copy16((char*)(BUF) + (wave * 4 + c) * 1024, g_);                     \
        }                                                                               \
    }
    bf16x8 xr, er;
    #define XLOAD(KC2) {                                                                \
        int k3_ = (KC2) >> 3, c8_ = (KC2) & 7;                                          \
        int kh_ = (k3_ * 11) >> 5, kw_ = k3_ - 3 * kh_;                                 \
        xr = *(const bf16x8*)(xb0 + (kh_ * 32 + c8_ * 4) * 528 + kw_ * 8);              \
        er = *(const bf16x8*)(enb + c8_ * 2048);                                        \
    }
    #define ZBUILD(ZBUF, KC1) {                                                         \
        int k3_ = (KC1) >> 3;                                                           \
        float ekv = ekl[k3_ * 64 + zpx];                                                \
        i32x4 zz;                                                                       \
        _Pragma("unroll")                                                               \
        for (int i = 0; i < 4; ++i) {                                                   \
            float q0 = __builtin_fmaf(ekv, bf2f(er[2 * i]),     1.0f);                  \
            float q1 = __builtin_fmaf(ekv, bf2f(er[2 * i + 1]), 1.0f);                  \
            zz[i] = cvt_pk_bf16(bf2f(xr[2 * i])     * __builtin_amdgcn_rcpf(q0),        \
                                bf2f(xr[2 * i + 1]) * __builtin_amdgcn_rcpf(q1));       \
        }                                                                               \
        *(i32x4*)((ZBUF) + wave * 512 + lane * 8) = zz;                                 \
    }

    // prologue
    DMA_B(0, Bl0)
    XLOAD(0)
    __syncthreads();          // ekl staged + B(0) drained
    ZBUILD(z0, 0)
    XLOAD(1)
    __syncthreads();          // z(0) visible

    f32x4 acc[4][4] = {};

    #pragma unroll 2
    for (int kc = 0; kc < 72; ++kc) {
        short* zcur = (kc & 1) ? z1 : z0;
        short* znxt = (kc & 1) ? z0 : z1;
        short* bcur = (kc & 1) ? Bl1 : Bl0;
        short* bnxt = (kc & 1) ? Bl0 : Bl1;
        if (kc < 71) {
            DMA_B(kc + 1, bnxt)       // in flight across this step; drained at barrier
            ZBUILD(znxt, kc + 1)
        }
        if (kc < 70) XLOAD(kc + 2)
        bf16x8 afr[4], bfr[4];
        #pragma unroll
        for (int mt = 0; mt < 4; ++mt)
            afr[mt] = *(const bf16x8*)(zcur + mt * 512 + lane * 8);
        #pragma unroll
        for (int nt = 0; nt < 4; ++nt)
            bfr[nt] = *(const bf16x8*)(bcur + (wave * 4 + nt) * 512 + lane * 8);
        __builtin_amdgcn_s_setprio(1);
        #pragma unroll
        for (int mt = 0; mt < 4; ++mt)
            #pragma unroll
            for (int nt = 0; nt < 4; ++nt)
                acc[mt][nt] = __builtin_amdgcn_mfma_f32_16x16x32_bf16(afr[mt], bfr[nt], acc[mt][nt], 0, 0, 0);
        __builtin_amdgcn_s_setprio(0);
        __syncthreads();
    }
    #undef ZBUILD
    #undef XLOAD
    #undef DMA_B

    // epilogue: per (mt,nt): o = wave*64 + nt*16 + l16 ; px = mt*16 + lg*4 + r
    #pragma unroll
    for (int mt = 0; mt < 4; ++mt)
        #pragma unroll
        for (int nt = 0; nt < 4; ++nt) {
            int o = wave * 64 + nt * 16 + l16;
            float* d = out + (((size_t)b * 256 + o) * 64 + h) * 64 + mt * 16 + lg * 4;
            *(f32x4*)d = acc[mt][nt];
        }
}

// ---------------- launcher ----------------
extern "C" void kernel_launch(void* const* d_in, const int* in_sizes, int n_in,
                              void* d_out, int out_size, void* d_ws, size_t ws_size,
                              hipStream_t stream) {
    const float* x    = (const float*)d_in[0];
    const float* w_c1 = (const float*)d_in[1];
    const float* b_c1 = (const float*)d_in[2];
    const float* w_c2 = (const float*)d_in[3];
    const float* b_c2 = (const float*)d_in[4];
    const float* w_d1 = (const float*)d_in[5];
    const float* b_d1 = (const float*)d_in[6];
    const float* w_d2 = (const float*)d_in[7];
    const float* b_d2 = (const float*)d_in[8];
    const float* Wt   = (const float*)d_in[9];
    float* out = (float*)d_out;
    char* ws = (char*)d_ws;

    short* wc1f = (short*)(ws + WS_WC1F);
    short* wc2f = (short*)(ws + WS_WC2F);
    short* wd1f = (short*)(ws + WS_WD1F);
    short* Wf   = (short*)(ws + WS_WF);
    float* ekT  = (float*)(ws + WS_EKT);
    short* enF  = (short*)(ws + WS_EN);
    short* xT8  = (short*)(ws + WS_XT);

    (void)hipFuncSetAttribute((const void*)k_branch, hipFuncAttributeMaxDynamicSharedMemorySize, BR_TOTAL);
    (void)hipFuncSetAttribute((const void*)k_final,  hipFuncAttributeMaxDynamicSharedMemorySize, FN3_TOTAL);

    k_prep<<<3008, 256, 0, stream>>>(Wt, w_d1, w_c1, w_c2, Wf, wd1f, wc1f, wc2f);
    k_prep_xt<<<512, 256, 0, stream>>>(x, xT8);
    k_branch<<<512, 512, BR_TOTAL, stream>>>(xT8, b_c1, b_c2, b_d1, w_d2, b_d2, wc1f, wc2f, wd1f, enF, ekT);
    k_final<<<512, 256, FN3_TOTAL, stream>>>(xT8, Wf, enF, ekT, out);
}